// Round 1
// baseline (397.102 us; speedup 1.0000x reference)
//
#include <hip/hip_runtime.h>

// SparseMeshConv fused kernel (MI355X / gfx950)
//   patch = [x, |a-c|, a+c, |b-d|, b+d]  (a=x[idx1], b=x[idx2], c=x[idx3], d=x[idx4])
//   y = LN(patch @ W + bias) * gamma + beta + x;  out = gelu_erf(y)
// GEMM M=100000 K=1280 N=256 via bf16 MFMA 16x16x32, fp32 accumulate.
// d_ws holds W pre-converted to bf16, tiled [kc][n][64] (640 KB).

#define N_ROWS   100000
#define C        256
#define BK       64
#define NCHUNK   20      // 1280 / 64
#define BM       64
#define LN_EPS   1e-5f
#define APAD     72      // 64 + 8 bf16 pad -> rows advance 4 banks (2-way alias, free)

typedef __bf16 bf16;
typedef bf16  bf16x8 __attribute__((ext_vector_type(8)));
typedef float f32x4  __attribute__((ext_vector_type(4)));

union BV { bf16x8 v; bf16 h[8]; };
union FV { float4 q[4]; float f[16]; };

// ---- prep: W [1280][256] fp32 -> Wt tiled bf16 [kc][n][kk] = W[kc*64+kk][n]
__global__ void wprep(const float* __restrict__ W, bf16* __restrict__ Wt) {
    int t = blockIdx.x * 256 + threadIdx.x;
    if (t >= NCHUNK * C * BK) return;
    int kc  = t / (C * BK);
    int rem = t - kc * (C * BK);
    int n   = rem >> 6;      // /64
    int kk  = rem & 63;
    Wt[t] = (bf16)W[(size_t)(kc * BK + kk) * C + n];
}

__global__ __launch_bounds__(256, 3)
void fused(const float* __restrict__ x,
           const int* __restrict__ idx1, const int* __restrict__ idx2,
           const int* __restrict__ idx3, const int* __restrict__ idx4,
           const bf16* __restrict__ Wt,
           const float* __restrict__ bias,
           const float* __restrict__ gamma_, const float* __restrict__ beta_,
           float* __restrict__ out)
{
    __shared__ __align__(16) bf16 Alds[BM * APAD];   //  9216 B
    __shared__ __align__(16) bf16 Wlds[C * APAD];    // 36864 B
    __shared__ int   gidx[4][BM];                    //  1024 B
    __shared__ float redsum[BM][4];                  //  1024 B
    __shared__ float redsq [BM][4];                  //  1024 B
    __shared__ float s_mu[BM], s_rs[BM];             //   512 B

    const int tid  = threadIdx.x;
    const int lane = tid & 63;
    const int wv   = tid >> 6;       // wave id -> column group (wv*64)
    const int quad = lane >> 4;
    const int l16  = lane & 15;
    const int r0   = blockIdx.x * BM;

    // ---- load gather indices for this block's 64 rows (256 threads = 4*64)
    {
        int which = tid >> 6;
        int r     = tid & 63;
        int gr    = r0 + r; if (gr >= N_ROWS) gr = 0;
        const int* ip = (which == 0) ? idx1 : (which == 1) ? idx2
                      : (which == 2) ? idx3 : idx4;
        gidx[which][r] = ip[gr];
    }

    f32x4 acc[4][4] = {};            // wave tile 64x64: 4 m-frags x 4 n-frags

    const int r_st = tid >> 2;       // staging: row 0..63
    const int q_st = tid & 3;        // staging: 16-float column quarter
    int gr_self = r0 + r_st; if (gr_self >= N_ROWS) gr_self = 0;

    for (int kc = 0; kc < NCHUNK; ++kc) {
        __syncthreads();             // also covers gidx visibility on iter 0

        // ---- stage A chunk [64 rows][64 k] -> bf16 LDS
        {
            const int seg = kc >> 2;                          // patch segment 0..4
            const int off = ((kc & 3) << 6) + (q_st << 4);    // col within segment
            FV u;
            if (seg == 0) {
                const float4* p = (const float4*)(x + (size_t)gr_self * C + off);
                #pragma unroll
                for (int j = 0; j < 4; ++j) u.q[j] = p[j];
            } else {
                const int ia = (seg <= 2) ? gidx[0][r_st] : gidx[1][r_st];
                const int ic = (seg <= 2) ? gidx[2][r_st] : gidx[3][r_st];
                const bool sab = (seg & 1);                   // 1,3: |diff|; 2,4: sum
                const float4* pa = (const float4*)(x + (size_t)ia * C + off);
                const float4* pc = (const float4*)(x + (size_t)ic * C + off);
                FV ua, uc;
                #pragma unroll
                for (int j = 0; j < 4; ++j) { ua.q[j] = pa[j]; uc.q[j] = pc[j]; }
                #pragma unroll
                for (int j = 0; j < 16; ++j)
                    u.f[j] = sab ? fabsf(ua.f[j] - uc.f[j]) : (ua.f[j] + uc.f[j]);
            }
            BV b0, b1;
            #pragma unroll
            for (int j = 0; j < 8; ++j) { b0.h[j] = (bf16)u.f[j]; b1.h[j] = (bf16)u.f[j + 8]; }
            bf16x8* dst = (bf16x8*)&Alds[r_st * APAD + (q_st << 4)];
            dst[0] = b0.v; dst[1] = b1.v;
        }

        // ---- stage W chunk [256 n][64 k] bf16 (coalesced 16B/lane from tiled Wt)
        {
            const bf16x8* src = (const bf16x8*)(Wt + (size_t)kc * (C * BK));
            #pragma unroll
            for (int j = 0; j < 8; ++j) {
                int g = tid + j * 256;                        // vector index 0..2047
                bf16x8 w = src[g];
                *(bf16x8*)&Wlds[(g >> 3) * APAD + ((g & 7) << 3)] = w;
            }
        }
        __syncthreads();

        // ---- MFMA: 2 k-steps of 32
        #pragma unroll
        for (int ks = 0; ks < 2; ++ks) {
            const int kb = ks * 32 + quad * 8;
            bf16x8 af[4], bfr[4];
            #pragma unroll
            for (int mi = 0; mi < 4; ++mi)
                af[mi] = *(const bf16x8*)&Alds[(mi * 16 + l16) * APAD + kb];
            #pragma unroll
            for (int ni = 0; ni < 4; ++ni)
                bfr[ni] = *(const bf16x8*)&Wlds[(wv * 64 + ni * 16 + l16) * APAD + kb];
            #pragma unroll
            for (int mi = 0; mi < 4; ++mi)
                #pragma unroll
                for (int ni = 0; ni < 4; ++ni)
                    acc[mi][ni] = __builtin_amdgcn_mfma_f32_16x16x32_bf16(
                        af[mi], bfr[ni], acc[mi][ni], 0, 0, 0);
        }
    }

    // ---- epilogue: +bias, row stats (sum / sumsq over 256 cols), LN, residual, GELU
    float bcol[4], gcol[4], ecol[4];
    #pragma unroll
    for (int ni = 0; ni < 4; ++ni) {
        int cidx = wv * 64 + ni * 16 + l16;
        bcol[ni] = bias[cidx]; gcol[ni] = gamma_[cidx]; ecol[ni] = beta_[cidx];
    }
    #pragma unroll
    for (int mi = 0; mi < 4; ++mi)
        #pragma unroll
        for (int ni = 0; ni < 4; ++ni)
            #pragma unroll
            for (int rg = 0; rg < 4; ++rg)
                acc[mi][ni][rg] += bcol[ni];

    #pragma unroll
    for (int mi = 0; mi < 4; ++mi) {
        #pragma unroll
        for (int rg = 0; rg < 4; ++rg) {
            float s = 0.f, q = 0.f;
            #pragma unroll
            for (int ni = 0; ni < 4; ++ni) {
                float y = acc[mi][ni][rg];
                s += y; q += y * y;
            }
            // butterfly across the 16 lanes holding this row's 64 cols
            #pragma unroll
            for (int m = 1; m <= 8; m <<= 1) {
                s += __shfl_xor(s, m, 64);
                q += __shfl_xor(q, m, 64);
            }
            if (l16 == 0) {
                int row = mi * 16 + quad * 4 + rg;
                redsum[row][wv] = s;
                redsq [row][wv] = q;
            }
        }
    }
    __syncthreads();
    if (tid < BM) {
        float s  = redsum[tid][0] + redsum[tid][1] + redsum[tid][2] + redsum[tid][3];
        float q  = redsq [tid][0] + redsq [tid][1] + redsq [tid][2] + redsq [tid][3];
        float mu = s * (1.0f / C);
        float var = q * (1.0f / C) - mu * mu;
        s_mu[tid] = mu;
        s_rs[tid] = rsqrtf(var + LN_EPS);
    }
    __syncthreads();

    #pragma unroll
    for (int mi = 0; mi < 4; ++mi) {
        #pragma unroll
        for (int rg = 0; rg < 4; ++rg) {
            int row  = mi * 16 + quad * 4 + rg;
            int grow = r0 + row;
            if (grow >= N_ROWS) continue;
            float mu = s_mu[row], rs = s_rs[row];
            #pragma unroll
            for (int ni = 0; ni < 4; ++ni) {
                int cidx = wv * 64 + ni * 16 + l16;
                float y = (acc[mi][ni][rg] - mu) * rs * gcol[ni] + ecol[ni];
                y += x[(size_t)grow * C + cidx];
                float g = 0.5f * y * (1.0f + erff(y * 0.70710678118654752f));
                out[(size_t)grow * C + cidx] = g;
            }
        }
    }
}

extern "C" void kernel_launch(void* const* d_in, const int* in_sizes, int n_in,
                              void* d_out, int out_size, void* d_ws, size_t ws_size,
                              hipStream_t stream) {
    const float* x  = (const float*)d_in[0];
    const int*   i1 = (const int*)d_in[1];
    const int*   i2 = (const int*)d_in[2];
    const int*   i3 = (const int*)d_in[3];
    const int*   i4 = (const int*)d_in[4];
    const float* W  = (const float*)d_in[5];
    const float* b  = (const float*)d_in[6];
    const float* gm = (const float*)d_in[7];
    const float* bt = (const float*)d_in[8];
    float* outp = (float*)d_out;
    bf16* Wt = (bf16*)d_ws;   // 20*256*64*2 = 640 KB

    wprep<<<(NCHUNK * C * BK + 255) / 256, 256, 0, stream>>>(W, Wt);
    fused<<<(N_ROWS + BM - 1) / BM, 256, 0, stream>>>(
        x, i1, i2, i3, i4, Wt, b, gm, bt, outp);
}